// Round 9
// baseline (149.315 us; speedup 1.0000x reference)
//
#include <hip/hip_runtime.h>

typedef unsigned short u16;
typedef short  bf16x8 __attribute__((ext_vector_type(8)));
typedef u16    u16x8  __attribute__((ext_vector_type(8)));
typedef float  f32x4  __attribute__((ext_vector_type(4)));
typedef float  f32x2  __attribute__((ext_vector_type(2)));
typedef int    i32x4  __attribute__((ext_vector_type(4)));
typedef unsigned u32x4 __attribute__((ext_vector_type(4)));

__device__ __forceinline__ u16 f2bf(float f) {
  union { float f; unsigned u; } x; x.f = f;
  return (u16)((x.u + 0x7fffu + ((x.u >> 16) & 1u)) >> 16);
}

__device__ __forceinline__ unsigned pk2bf(float a, float b) {
  unsigned r;
  asm("v_cvt_pk_bf16_f32 %0, %1, %2" : "=v"(r) : "v"(a), "v"(b));
  return r;
}

__device__ __forceinline__ float exp2v(float x) {
  float r;
  asm("v_exp_f32 %0, %1" : "=v"(r) : "v"(x));
  return r;
}

// async global->LDS, 16B per lane; lds base wave-uniform (HW adds lane*16)
__device__ __forceinline__ void gload16(const void* g, void* lds) {
  __builtin_amdgcn_global_load_lds((const __attribute__((address_space(1))) unsigned int*)g,
                                   (__attribute__((address_space(3))) unsigned int*)lds,
                                   16, 0, 0);
}

// ---- 64-col tiles (128B rows): XOR-swizzled b128 read ----
__device__ __forceinline__ bf16x8 lds8(const u16* base, int row, int colb) {
  int off = (row << 7) + colb;
  off ^= (row & 7) << 4;
  return *(const bf16x8*)((const char*)base + off);
}

// ---- 32-col tiles (64B rows), GEMM BK=32: 4-slot XOR swizzle ----
__device__ __forceinline__ bf16x8 lds32(const u16* base, int row, int lg) {
  int off = (row << 6) + ((lg ^ (row & 3)) << 4);
  return *(const bf16x8*)((const char*)base + off);
}

// ---------------- prep kernels ----------------

__global__ __launch_bounds__(256) void cast_x_k(const float* __restrict__ x,
                                                u16* __restrict__ xb) {
  int i = (blockIdx.x * 256 + threadIdx.x) * 8;
  float4 a = *(const float4*)&x[i];
  float4 b = *(const float4*)&x[i + 4];
  u16x8 o;
  o[0] = f2bf(a.x); o[1] = f2bf(a.y); o[2] = f2bf(a.z); o[3] = f2bf(a.w);
  o[4] = f2bf(b.x); o[5] = f2bf(b.y); o[6] = f2bf(b.z); o[7] = f2bf(b.w);
  *(u16x8*)&xb[i] = o;
}

__global__ __launch_bounds__(256) void transpose_cast_k(const float* __restrict__ Wq,
                                                        const float* __restrict__ Wk,
                                                        const float* __restrict__ Wv,
                                                        const float* __restrict__ Wo,
                                                        u16* __restrict__ WqkvT,
                                                        u16* __restrict__ WoT) {
  __shared__ u16 tile[64][72];
  int z = blockIdx.z;
  const float* W = (z == 0) ? Wq : (z == 1) ? Wk : (z == 2) ? Wv : Wo;
  u16* dst = (z < 3) ? (WqkvT + z * 1024 * 1024) : WoT;
  int k0 = blockIdx.y << 6, nn0 = blockIdx.x << 6;
  int t = threadIdx.x;
#pragma unroll
  for (int p = 0; p < 4; ++p) {
    int kr = (p << 4) + (t >> 4), c4 = (t & 15) << 2;
    float4 v = *(const float4*)&W[(k0 + kr) * 1024 + nn0 + c4];
    tile[c4 + 0][kr] = f2bf(v.x); tile[c4 + 1][kr] = f2bf(v.y);
    tile[c4 + 2][kr] = f2bf(v.z); tile[c4 + 3][kr] = f2bf(v.w);
  }
  __syncthreads();
#pragma unroll
  for (int p = 0; p < 2; ++p) {
    int nr = (p << 5) + (t >> 3), c8 = (t & 7) << 3;
    i32x4 vv = *(const i32x4*)&tile[nr][c8];
    *(i32x4*)&dst[(nn0 + nr) * 1024 + k0 + c8] = vv;
  }
}

__global__ __launch_bounds__(256) void rope_table_k(f32x2* __restrict__ ctab) {
  int idx = blockIdx.x * 256 + threadIdx.x;   // pos*32 + i
  int i = idx & 31, p = idx >> 5;
  float freq = powf(10000.0f, -(float)(2 * i) * (1.0f / 64.0f));
  float ang = (float)p * freq;
  f32x2 v; v[0] = cosf(ang); v[1] = sinf(ang);
  ctab[idx] = v;
}

// ---------------- fused QKV GEMM ----------------
// 128x128 tile, BK=32, 3 LDS buffers, 2-deep prefetch, counted vmcnt.
// n-region 0: Q (RoPE * 0.125*log2e), 1: K (RoPE), 2: V (store transposed per-(b,h),
// keys sigma-permuted within each 64-block so attn PV B-frags are single b128 reads).

__global__ __launch_bounds__(256) void gemm_qkv_k(const u16* __restrict__ A,
                                                  const u16* __restrict__ BT,
                                                  u16* __restrict__ Qb,
                                                  u16* __restrict__ Kb,
                                                  u16* __restrict__ VbT,
                                                  const f32x2* __restrict__ ctab) {
  __shared__ u16 As[3][128 * 32];
  __shared__ u16 Bs[3][128 * 32];
  const int K = 1024;
  const int m0 = blockIdx.y << 7, n0 = blockIdx.x << 7;
  const int t = threadIdx.x, w = t >> 6, l = t & 63;
  const int wr = (w >> 1) << 6, wc = (w & 1) << 6;
  const int lr = l & 15, lg = l >> 4;
  const int g_row = l >> 2;
  const int g_col = (((l & 3) ^ ((l >> 2) & 3)) << 3);

  auto stage = [&](int buf, int kt) {
    const int k0_ = kt << 5;
#pragma unroll
    for (int it = 0; it < 2; ++it) {
      int seg = (w << 1) + it;
      int row = (seg << 4) + g_row;
      gload16(&A[(m0 + row) * K + k0_ + g_col], (char*)As[buf] + seg * 1024);
      gload16(&BT[(n0 + row) * K + k0_ + g_col], (char*)Bs[buf] + seg * 1024);
    }
  };

  f32x4 acc[4][4] = {};

  stage(0, 0);
  stage(1, 1);

#pragma unroll
  for (int kt = 0; kt < 32; ++kt) {
    if (kt < 31) asm volatile("s_waitcnt vmcnt(4)" ::: "memory");
    else         asm volatile("s_waitcnt vmcnt(0)" ::: "memory");
    __builtin_amdgcn_s_barrier();
    __builtin_amdgcn_sched_barrier(0);
    if (kt < 30) stage((kt + 2) % 3, kt + 2);
    const u16* Ab = As[kt % 3];
    const u16* Bb = Bs[kt % 3];
    bf16x8 af[4], bfr[4];
#pragma unroll
    for (int m = 0; m < 4; ++m) af[m] = lds32(Ab, wr + (m << 4) + lr, lg);
#pragma unroll
    for (int n = 0; n < 4; ++n) bfr[n] = lds32(Bb, wc + (n << 4) + lr, lg);
#pragma unroll
    for (int m = 0; m < 4; ++m)
#pragma unroll
      for (int n = 0; n < 4; ++n)
        acc[m][n] = __builtin_amdgcn_mfma_f32_16x16x32_bf16(af[m], bfr[n], acc[m][n], 0, 0, 0);
  }

  const int region = n0 >> 10;
  if (region < 2) {
    const float qscale = 0.125f * 1.44269504088896f;
#pragma unroll
    for (int m = 0; m < 4; ++m)
#pragma unroll
      for (int n = 0; n < 4; ++n) {
        const int col = n0 + wc + (n << 4) + lr;
        const int hd = col & 63;
#pragma unroll
        for (int r = 0; r < 4; ++r) {
          const int row = m0 + wr + (m << 4) + (lg << 2) + r;
          float v = acc[m][n][r];
          float p = __shfl_xor(v, 1);
          f32x2 cs = ctab[(row & 2047) * 32 + (hd >> 1)];
          float o = (hd & 1) ? (p * cs[1] + v * cs[0]) : (v * cs[0] - p * cs[1]);
          if (region == 0) { o *= qscale; Qb[row * 1024 + (col & 1023)] = f2bf(o); }
          else             { Kb[row * 1024 + (col & 1023)] = f2bf(o); }
        }
      }
  } else {
#pragma unroll
    for (int m = 0; m < 4; ++m)
#pragma unroll
      for (int n = 0; n < 4; ++n) {
        const int cv = n0 + wc + (n << 4) + lr - 2048;
        const int hh = cv >> 6, dim = cv & 63;
#pragma unroll
        for (int r = 0; r < 4; ++r) {
          const int row = m0 + wr + (m << 4) + (lg << 2) + r;
          const int bb = row >> 11, pos = row & 2047;
          // sigma key-permute within each 64-key block
          const int k6 = pos & 63;
          const int pp = (k6 & 3) | (((k6 >> 4) & 1) << 2) | (((k6 >> 2) & 3) << 3)
                       | (((k6 >> 5) & 1) << 5);
          const int posp = (pos & ~63) | pp;
          VbT[(((bb << 4) + hh) << 6 | dim) * 2048 + posp] = f2bf(acc[m][n][r]);
        }
      }
  }
}

// ---------------- output GEMM: out = Ob * WoT^T, fp32 out ----------------

__global__ __launch_bounds__(256) void gemm_out_k(const u16* __restrict__ A,
                                                  const u16* __restrict__ BT,
                                                  float* __restrict__ C) {
  __shared__ u16 As[3][64 * 32];
  __shared__ u16 Bs[3][128 * 32];
  const int K = 1024;
  const int m0 = blockIdx.y << 6, n0 = blockIdx.x << 7;
  const int t = threadIdx.x, w = t >> 6, l = t & 63;
  const int wr = (w & 1) << 5, wc = (w >> 1) << 6;
  const int lr = l & 15, lg = l >> 4;
  const int g_row = l >> 2;
  const int g_col = (((l & 3) ^ ((l >> 2) & 3)) << 3);

  auto stage = [&](int buf, int kt) {
    const int k0_ = kt << 5;
    {
      int rowA = (w << 4) + g_row;
      gload16(&A[(m0 + rowA) * K + k0_ + g_col], (char*)As[buf] + w * 1024);
    }
#pragma unroll
    for (int it = 0; it < 2; ++it) {
      int seg = (w << 1) + it;
      int row = (seg << 4) + g_row;
      gload16(&BT[(n0 + row) * K + k0_ + g_col], (char*)Bs[buf] + seg * 1024);
    }
  };

  f32x4 acc[2][4] = {};

  stage(0, 0);
  stage(1, 1);

#pragma unroll
  for (int kt = 0; kt < 32; ++kt) {
    if (kt < 31) asm volatile("s_waitcnt vmcnt(3)" ::: "memory");
    else         asm volatile("s_waitcnt vmcnt(0)" ::: "memory");
    __builtin_amdgcn_s_barrier();
    __builtin_amdgcn_sched_barrier(0);
    if (kt < 30) stage((kt + 2) % 3, kt + 2);
    const u16* Ab = As[kt % 3];
    const u16* Bb = Bs[kt % 3];
    bf16x8 af[2], bfr[4];
#pragma unroll
    for (int m = 0; m < 2; ++m) af[m] = lds32(Ab, wr + (m << 4) + lr, lg);
#pragma unroll
    for (int n = 0; n < 4; ++n) bfr[n] = lds32(Bb, wc + (n << 4) + lr, lg);
#pragma unroll
    for (int m = 0; m < 2; ++m)
#pragma unroll
      for (int n = 0; n < 4; ++n)
        acc[m][n] = __builtin_amdgcn_mfma_f32_16x16x32_bf16(af[m], bfr[n], acc[m][n], 0, 0, 0);
  }

#pragma unroll
  for (int m = 0; m < 2; ++m)
#pragma unroll
    for (int n = 0; n < 4; ++n) {
      const int col = n0 + wc + (n << 4) + lr;
#pragma unroll
      for (int r = 0; r < 4; ++r) {
        const int row = m0 + wr + (m << 4) + (lg << 2) + r;
        C[row * 1024 + col] = acc[m][n][r];
      }
    }
}

// ---------------- flash attention ----------------
// grid 512 (XCD-swizzled), 256 threads = 4 waves; wave owns 32 q-rows (2 groups).
// Q and K direct in registers (K: 8 dwordx4 gathers/tile from L1/L2-resident panel;
// A/B register double-buffer via 2x-unrolled loop). V only in LDS: 3 buffers,
// sigma-global layout -> single-b128 frags, zero conflicts. Per phase:
// issue kf(next), stage V(+2), QK, exp2/pack, PV, vmcnt(2) (never 0), barrier.

__global__ __launch_bounds__(256) void attn_k(const u16* __restrict__ Qb,
                                              const u16* __restrict__ Kb,
                                              const u16* __restrict__ VbT,
                                              u16* __restrict__ Ob) {
  __shared__ u16 Vs[3][64 * 64];   // [dim][key-sigma]

  const int lin = blockIdx.x;
  const int xcd = lin & 7, rest = lin >> 3;
  const int bh = (xcd << 2) + (rest & 3);     // 4 bh per XCD -> K/V L2-resident
  const int qt = rest >> 2;                   // 0..15
  const int b = bh >> 4;
  const int t = threadIdx.x, w = t >> 6, l = t & 63;
  const int lr = l & 15, lg = l >> 4;
  const int rb = b << 11;
  const int cb = (bh & 15) << 6;
  const int srow = l >> 3;
  const int scol = ((l & 7) ^ srow) << 3;

  // per-lane K gather base: row (rb + lr), col cb + lg*8
  const u16* Kbase = Kb + (size_t)(rb + lr) * 1024 + cb + (lg << 3);

  auto load_kf = [&](bf16x8 (&dst)[4][2], int tile) {
    const int tt = tile > 31 ? 31 : tile;
#pragma unroll
    for (int c = 0; c < 4; ++c)
#pragma unroll
      for (int kk = 0; kk < 2; ++kk)
        dst[c][kk] = *(const bf16x8*)&Kbase[(size_t)((tt << 6) + (c << 4)) * 1024 + (kk << 5)];
  };

  auto v_stage = [&](u16* bufp, int tile) {
    const int tt = tile > 31 ? 31 : tile;
#pragma unroll
    for (int it = 0; it < 2; ++it) {
      int seg = (w << 1) + it;
      int row = (seg << 3) + srow;
      gload16(&VbT[((bh << 6) + row) * 2048 + (tt << 6) + scol], (char*)bufp + seg * 1024);
    }
  };

  // Q direct to registers: qf[g][kk] = Q[qt*128 + w*32 + g*16 + lr][cb + kk*32 + lg*8 ..)
  bf16x8 qf[2][2];
#pragma unroll
  for (int g = 0; g < 2; ++g)
#pragma unroll
    for (int kk = 0; kk < 2; ++kk)
      qf[g][kk] = *(const bf16x8*)&Qb[(size_t)(rb + (qt << 7) + (w << 5) + (g << 4) + lr) * 1024
                                      + cb + (kk << 5) + (lg << 3)];

  bf16x8 kfA[4][2], kfB[4][2];
  load_kf(kfA, 0);                    // 8 reg loads
  v_stage(Vs[0], 0);                  // 2 lds loads
  v_stage(Vs[1], 1);                  // 2 lds loads
  asm volatile("s_waitcnt vmcnt(2)" ::: "memory");   // qf+kfA+V0 done, V1 flying
  __builtin_amdgcn_s_barrier();
  __builtin_amdgcn_sched_barrier(0);

  const f32x4 z4 = {0.f, 0.f, 0.f, 0.f};
  float lsum[2] = {0.f, 0.f};
  f32x4 Oacc[2][4] = {};   // [g][df]

  u16* p0 = Vs[0];   // buf for tile kt
  u16* p1 = Vs[1];   // buf for tile kt+1
  u16* p2 = Vs[2];   // stage target for kt+2

  auto phase = [&](const bf16x8 (&kfU)[4][2], bf16x8 (&kfL)[4][2],
                   const u16* vcur, u16* vstg, int ktNext, int ktStage) {
    load_kf(kfL, ktNext);
    v_stage(vstg, ktStage);
    unsigned U[2][4][2];
#pragma unroll
    for (int c = 0; c < 4; ++c) {
      f32x4 S[2];
      __builtin_amdgcn_s_setprio(1);
#pragma unroll
      for (int g = 0; g < 2; ++g) {
        S[g] = __builtin_amdgcn_mfma_f32_16x16x32_bf16(kfU[c][0], qf[g][0], z4, 0, 0, 0);
        S[g] = __builtin_amdgcn_mfma_f32_16x16x32_bf16(kfU[c][1], qf[g][1], S[g], 0, 0, 0);
      }
      __builtin_amdgcn_s_setprio(0);
#pragma unroll
      for (int g = 0; g < 2; ++g) {
        float q0 = exp2v(S[g][0]), q1 = exp2v(S[g][1]);
        float q2 = exp2v(S[g][2]), q3 = exp2v(S[g][3]);
        lsum[g] += (q0 + q1) + (q2 + q3);
        U[g][c][0] = pk2bf(q0, q1);
        U[g][c][1] = pk2bf(q2, q3);
      }
    }
#pragma unroll
    for (int kk2 = 0; kk2 < 2; ++kk2) {
      bf16x8 vf[4];
#pragma unroll
      for (int df = 0; df < 4; ++df)
        vf[df] = lds8(vcur, (df << 4) + lr, (kk2 << 6) + (lg << 4));
      __builtin_amdgcn_s_setprio(1);
#pragma unroll
      for (int g = 0; g < 2; ++g) {
        u32x4 pt;
        pt[0] = U[g][2 * kk2][0];     pt[1] = U[g][2 * kk2][1];
        pt[2] = U[g][2 * kk2 + 1][0]; pt[3] = U[g][2 * kk2 + 1][1];
        bf16x8 pa = *(const bf16x8*)&pt;
#pragma unroll
        for (int df = 0; df < 4; ++df)
          Oacc[g][df] = __builtin_amdgcn_mfma_f32_16x16x32_bf16(pa, vf[df], Oacc[g][df], 0, 0, 0);
      }
      __builtin_amdgcn_s_setprio(0);
    }
    asm volatile("s_waitcnt vmcnt(2)" ::: "memory");
    __builtin_amdgcn_s_barrier();
    __builtin_amdgcn_sched_barrier(0);
  };

  for (int kt = 0; kt < 32; kt += 2) {
    // even phase: compute tile kt  (kfA, p0); prefetch kf(kt+1), V(kt+2)->p2
    phase(kfA, kfB, p0, p2, kt + 1, kt + 2);
    // odd phase: compute tile kt+1 (kfB, p1); prefetch kf(kt+2), V(kt+3)->p0's buf
    phase(kfB, kfA, p1, p0, kt + 2, kt + 3);
    // rotate: (p0,p1,p2) <- (p2,p0,p1)
    u16* tmp = p2; p2 = p1; p1 = p0; p0 = tmp;
  }

  // epilogue per group: reduce lsum across lg-halves, normalize, store
#pragma unroll
  for (int g = 0; g < 2; ++g) {
    float ls = lsum[g];
    ls += __shfl_xor(ls, 16);
    ls += __shfl_xor(ls, 32);
    float lq[4];
#pragma unroll
    for (int r = 0; r < 4; ++r) lq[r] = 1.f / __shfl(ls, (lg << 2) + r);
#pragma unroll
    for (int df = 0; df < 4; ++df)
#pragma unroll
      for (int r = 0; r < 4; ++r) {
        int row = (qt << 7) + (w << 5) + (g << 4) + (lg << 2) + r;
        int col = (df << 4) + lr;
        Ob[(size_t)(rb + row) * 1024 + cb + col] = f2bf(Oacc[g][df][r] * lq[r]);
      }
  }
}

// ---------------- launcher ----------------

extern "C" void kernel_launch(void* const* d_in, const int* in_sizes, int n_in,
                              void* d_out, int out_size, void* d_ws, size_t ws_size,
                              hipStream_t stream) {
  const float* x  = (const float*)d_in[0];
  const float* Wq = (const float*)d_in[1];
  const float* Wk = (const float*)d_in[2];
  const float* Wv = (const float*)d_in[3];
  const float* Wo = (const float*)d_in[4];
  float* out = (float*)d_out;

  char* ws = (char*)d_ws;
  u16* xb     = (u16*)(ws);                 // 8 MB (reused as Ob)
  u16* WqkvT  = (u16*)(ws + 8388608);       // 6 MB  [3072][1024]
  u16* WoT    = (u16*)(ws + 14680064);      // 2 MB
  u16* Qb     = (u16*)(ws + 16777216);      // 8 MB
  u16* Kb     = (u16*)(ws + 25165824);      // 8 MB
  u16* VbT    = (u16*)(ws + 33554432);      // 8 MB  [bh*64+dim][2048 pos, sigma-permuted]
  f32x2* ctab = (f32x2*)(ws + 41943040);    // 512 KB
  u16* Ob = xb;

  cast_x_k<<<2048, 256, 0, stream>>>(x, xb);
  dim3 gt(16, 16, 4);
  transpose_cast_k<<<gt, 256, 0, stream>>>(Wq, Wk, Wv, Wo, WqkvT, WoT);
  rope_table_k<<<256, 256, 0, stream>>>(ctab);

  dim3 gq(24, 32);
  gemm_qkv_k<<<gq, 256, 0, stream>>>(xb, WqkvT, Qb, Kb, VbT, ctab);

  attn_k<<<512, 256, 0, stream>>>(Qb, Kb, VbT, Ob);

  dim3 go(8, 64);
  gemm_out_k<<<go, 256, 0, stream>>>(Ob, WoT, out);
}

// Round 10
// 120.607 us; speedup vs baseline: 1.2380x; 1.2380x over previous
//
#include <hip/hip_runtime.h>

typedef unsigned short u16;
typedef short  bf16x8 __attribute__((ext_vector_type(8)));
typedef u16    u16x8  __attribute__((ext_vector_type(8)));
typedef float  f32x4  __attribute__((ext_vector_type(4)));
typedef float  f32x2  __attribute__((ext_vector_type(2)));
typedef int    i32x4  __attribute__((ext_vector_type(4)));
typedef unsigned u32x4 __attribute__((ext_vector_type(4)));

__device__ __forceinline__ u16 f2bf(float f) {
  union { float f; unsigned u; } x; x.f = f;
  return (u16)((x.u + 0x7fffu + ((x.u >> 16) & 1u)) >> 16);
}

__device__ __forceinline__ unsigned pk2bf(float a, float b) {
  unsigned r;
  asm("v_cvt_pk_bf16_f32 %0, %1, %2" : "=v"(r) : "v"(a), "v"(b));
  return r;
}

__device__ __forceinline__ float exp2v(float x) {
  float r;
  asm("v_exp_f32 %0, %1" : "=v"(r) : "v"(x));
  return r;
}

// async global->LDS, 16B per lane; lds base wave-uniform (HW adds lane*16)
__device__ __forceinline__ void gload16(const void* g, void* lds) {
  __builtin_amdgcn_global_load_lds((const __attribute__((address_space(1))) unsigned int*)g,
                                   (__attribute__((address_space(3))) unsigned int*)lds,
                                   16, 0, 0);
}

// ---- 64-col tiles (128B rows): XOR-swizzled b128 read ----
__device__ __forceinline__ bf16x8 lds8(const u16* base, int row, int colb) {
  int off = (row << 7) + colb;
  off ^= (row & 7) << 4;
  return *(const bf16x8*)((const char*)base + off);
}

// ---- 32-col tiles (64B rows), GEMM BK=32: 4-slot XOR swizzle ----
__device__ __forceinline__ bf16x8 lds32(const u16* base, int row, int lg) {
  int off = (row << 6) + ((lg ^ (row & 3)) << 4);
  return *(const bf16x8*)((const char*)base + off);
}

// ---------------- prep kernels ----------------

__global__ __launch_bounds__(256) void cast_x_k(const float* __restrict__ x,
                                                u16* __restrict__ xb) {
  int i = (blockIdx.x * 256 + threadIdx.x) * 8;
  float4 a = *(const float4*)&x[i];
  float4 b = *(const float4*)&x[i + 4];
  u16x8 o;
  o[0] = f2bf(a.x); o[1] = f2bf(a.y); o[2] = f2bf(a.z); o[3] = f2bf(a.w);
  o[4] = f2bf(b.x); o[5] = f2bf(b.y); o[6] = f2bf(b.z); o[7] = f2bf(b.w);
  *(u16x8*)&xb[i] = o;
}

__global__ __launch_bounds__(256) void transpose_cast_k(const float* __restrict__ Wq,
                                                        const float* __restrict__ Wk,
                                                        const float* __restrict__ Wv,
                                                        const float* __restrict__ Wo,
                                                        u16* __restrict__ WqkvT,
                                                        u16* __restrict__ WoT) {
  __shared__ u16 tile[64][72];
  int z = blockIdx.z;
  const float* W = (z == 0) ? Wq : (z == 1) ? Wk : (z == 2) ? Wv : Wo;
  u16* dst = (z < 3) ? (WqkvT + z * 1024 * 1024) : WoT;
  int k0 = blockIdx.y << 6, nn0 = blockIdx.x << 6;
  int t = threadIdx.x;
#pragma unroll
  for (int p = 0; p < 4; ++p) {
    int kr = (p << 4) + (t >> 4), c4 = (t & 15) << 2;
    float4 v = *(const float4*)&W[(k0 + kr) * 1024 + nn0 + c4];
    tile[c4 + 0][kr] = f2bf(v.x); tile[c4 + 1][kr] = f2bf(v.y);
    tile[c4 + 2][kr] = f2bf(v.z); tile[c4 + 3][kr] = f2bf(v.w);
  }
  __syncthreads();
#pragma unroll
  for (int p = 0; p < 2; ++p) {
    int nr = (p << 5) + (t >> 3), c8 = (t & 7) << 3;
    i32x4 vv = *(const i32x4*)&tile[nr][c8];
    *(i32x4*)&dst[(nn0 + nr) * 1024 + k0 + c8] = vv;
  }
}

__global__ __launch_bounds__(256) void rope_table_k(f32x2* __restrict__ ctab) {
  int idx = blockIdx.x * 256 + threadIdx.x;   // pos*32 + i
  int i = idx & 31, p = idx >> 5;
  float freq = powf(10000.0f, -(float)(2 * i) * (1.0f / 64.0f));
  float ang = (float)p * freq;
  f32x2 v; v[0] = cosf(ang); v[1] = sinf(ang);
  ctab[idx] = v;
}

// ---------------- fused QKV GEMM ----------------
// 128x128 tile, BK=32, 3 LDS buffers, 2-deep prefetch, counted vmcnt.
// n-region 0: Q (RoPE * 0.125*log2e), 1: K (RoPE), 2: V (store transposed per-(b,h),
// keys sigma-permuted within each 64-block so attn PV B-frags are single b128 reads).

__global__ __launch_bounds__(256) void gemm_qkv_k(const u16* __restrict__ A,
                                                  const u16* __restrict__ BT,
                                                  u16* __restrict__ Qb,
                                                  u16* __restrict__ Kb,
                                                  u16* __restrict__ VbT,
                                                  const f32x2* __restrict__ ctab) {
  __shared__ u16 As[3][128 * 32];
  __shared__ u16 Bs[3][128 * 32];
  const int K = 1024;
  const int m0 = blockIdx.y << 7, n0 = blockIdx.x << 7;
  const int t = threadIdx.x, w = t >> 6, l = t & 63;
  const int wr = (w >> 1) << 6, wc = (w & 1) << 6;
  const int lr = l & 15, lg = l >> 4;
  const int g_row = l >> 2;
  const int g_col = (((l & 3) ^ ((l >> 2) & 3)) << 3);

  auto stage = [&](int buf, int kt) {
    const int k0_ = kt << 5;
#pragma unroll
    for (int it = 0; it < 2; ++it) {
      int seg = (w << 1) + it;
      int row = (seg << 4) + g_row;
      gload16(&A[(m0 + row) * K + k0_ + g_col], (char*)As[buf] + seg * 1024);
      gload16(&BT[(n0 + row) * K + k0_ + g_col], (char*)Bs[buf] + seg * 1024);
    }
  };

  f32x4 acc[4][4] = {};

  stage(0, 0);
  stage(1, 1);

#pragma unroll
  for (int kt = 0; kt < 32; ++kt) {
    if (kt < 31) asm volatile("s_waitcnt vmcnt(4)" ::: "memory");
    else         asm volatile("s_waitcnt vmcnt(0)" ::: "memory");
    __builtin_amdgcn_s_barrier();
    __builtin_amdgcn_sched_barrier(0);
    if (kt < 30) stage((kt + 2) % 3, kt + 2);
    const u16* Ab = As[kt % 3];
    const u16* Bb = Bs[kt % 3];
    bf16x8 af[4], bfr[4];
#pragma unroll
    for (int m = 0; m < 4; ++m) af[m] = lds32(Ab, wr + (m << 4) + lr, lg);
#pragma unroll
    for (int n = 0; n < 4; ++n) bfr[n] = lds32(Bb, wc + (n << 4) + lr, lg);
#pragma unroll
    for (int m = 0; m < 4; ++m)
#pragma unroll
      for (int n = 0; n < 4; ++n)
        acc[m][n] = __builtin_amdgcn_mfma_f32_16x16x32_bf16(af[m], bfr[n], acc[m][n], 0, 0, 0);
  }

  const int region = n0 >> 10;
  if (region < 2) {
    const float qscale = 0.125f * 1.44269504088896f;
#pragma unroll
    for (int m = 0; m < 4; ++m)
#pragma unroll
      for (int n = 0; n < 4; ++n) {
        const int col = n0 + wc + (n << 4) + lr;
        const int hd = col & 63;
#pragma unroll
        for (int r = 0; r < 4; ++r) {
          const int row = m0 + wr + (m << 4) + (lg << 2) + r;
          float v = acc[m][n][r];
          float p = __shfl_xor(v, 1);
          f32x2 cs = ctab[(row & 2047) * 32 + (hd >> 1)];
          float o = (hd & 1) ? (p * cs[1] + v * cs[0]) : (v * cs[0] - p * cs[1]);
          if (region == 0) { o *= qscale; Qb[row * 1024 + (col & 1023)] = f2bf(o); }
          else             { Kb[row * 1024 + (col & 1023)] = f2bf(o); }
        }
      }
  } else {
#pragma unroll
    for (int m = 0; m < 4; ++m)
#pragma unroll
      for (int n = 0; n < 4; ++n) {
        const int cv = n0 + wc + (n << 4) + lr - 2048;
        const int hh = cv >> 6, dim = cv & 63;
#pragma unroll
        for (int r = 0; r < 4; ++r) {
          const int row = m0 + wr + (m << 4) + (lg << 2) + r;
          const int bb = row >> 11, pos = row & 2047;
          // sigma key-permute within each 64-key block
          const int k6 = pos & 63;
          const int pp = (k6 & 3) | (((k6 >> 4) & 1) << 2) | (((k6 >> 2) & 3) << 3)
                       | (((k6 >> 5) & 1) << 5);
          const int posp = (pos & ~63) | pp;
          VbT[(((bb << 4) + hh) << 6 | dim) * 2048 + posp] = f2bf(acc[m][n][r]);
        }
      }
  }
}

// ---------------- output GEMM: out = Ob * WoT^T, fp32 out ----------------

__global__ __launch_bounds__(256) void gemm_out_k(const u16* __restrict__ A,
                                                  const u16* __restrict__ BT,
                                                  float* __restrict__ C) {
  __shared__ u16 As[3][64 * 32];
  __shared__ u16 Bs[3][128 * 32];
  const int K = 1024;
  const int m0 = blockIdx.y << 6, n0 = blockIdx.x << 7;
  const int t = threadIdx.x, w = t >> 6, l = t & 63;
  const int wr = (w & 1) << 5, wc = (w >> 1) << 6;
  const int lr = l & 15, lg = l >> 4;
  const int g_row = l >> 2;
  const int g_col = (((l & 3) ^ ((l >> 2) & 3)) << 3);

  auto stage = [&](int buf, int kt) {
    const int k0_ = kt << 5;
    {
      int rowA = (w << 4) + g_row;
      gload16(&A[(m0 + rowA) * K + k0_ + g_col], (char*)As[buf] + w * 1024);
    }
#pragma unroll
    for (int it = 0; it < 2; ++it) {
      int seg = (w << 1) + it;
      int row = (seg << 4) + g_row;
      gload16(&BT[(n0 + row) * K + k0_ + g_col], (char*)Bs[buf] + seg * 1024);
    }
  };

  f32x4 acc[2][4] = {};

  stage(0, 0);
  stage(1, 1);

#pragma unroll
  for (int kt = 0; kt < 32; ++kt) {
    if (kt < 31) asm volatile("s_waitcnt vmcnt(3)" ::: "memory");
    else         asm volatile("s_waitcnt vmcnt(0)" ::: "memory");
    __builtin_amdgcn_s_barrier();
    __builtin_amdgcn_sched_barrier(0);
    if (kt < 30) stage((kt + 2) % 3, kt + 2);
    const u16* Ab = As[kt % 3];
    const u16* Bb = Bs[kt % 3];
    bf16x8 af[2], bfr[4];
#pragma unroll
    for (int m = 0; m < 2; ++m) af[m] = lds32(Ab, wr + (m << 4) + lr, lg);
#pragma unroll
    for (int n = 0; n < 4; ++n) bfr[n] = lds32(Bb, wc + (n << 4) + lr, lg);
#pragma unroll
    for (int m = 0; m < 2; ++m)
#pragma unroll
      for (int n = 0; n < 4; ++n)
        acc[m][n] = __builtin_amdgcn_mfma_f32_16x16x32_bf16(af[m], bfr[n], acc[m][n], 0, 0, 0);
  }

#pragma unroll
  for (int m = 0; m < 2; ++m)
#pragma unroll
    for (int n = 0; n < 4; ++n) {
      const int col = n0 + wc + (n << 4) + lr;
#pragma unroll
      for (int r = 0; r < 4; ++r) {
        const int row = m0 + wr + (m << 4) + (lg << 2) + r;
        C[row * 1024 + col] = acc[m][n][r];
      }
    }
}

// ---------------- flash attention ----------------
// grid 512 (XCD-swizzled), 256 threads = 4 waves; wave owns 32 q-rows (2 groups).
// Q in registers. K and sigma-V both in LDS. SUPER-TILES of 128 keys (2x64 sub-tiles):
// one stage + one vmcnt(0)+barrier per super-tile (16 phases total). Phase length
// (~4000 cyc) >> load latency, so drain-to-0 staging is nearly free and the fixed
// per-phase stall amortizes over 2x the work. Zero-C softmax, in-register P.

__global__ __launch_bounds__(256) void attn_k(const u16* __restrict__ Qb,
                                              const u16* __restrict__ Kb,
                                              const u16* __restrict__ VbT,
                                              u16* __restrict__ Ob) {
  __shared__ u16 Ks[2][2][64 * 64];   // [buf][sub][key][dim]
  __shared__ u16 Vs[2][2][64 * 64];   // [buf][sub][dim][key-sigma]

  const int lin = blockIdx.x;
  const int xcd = lin & 7, rest = lin >> 3;
  const int bh = (xcd << 2) + (rest & 3);     // 4 bh per XCD -> K/V L2-resident
  const int qt = rest >> 2;                   // 0..15
  const int b = bh >> 4;
  const int t = threadIdx.x, w = t >> 6, l = t & 63;
  const int lr = l & 15, lg = l >> 4;
  const int rb = b << 11;
  const int cb = (bh & 15) << 6;
  const int srow = l >> 3;
  const int scol = ((l & 7) ^ srow) << 3;

  // stage one 128-key super-tile (2 sub-tiles of 64): 8 gload16 per wave
  auto kv_stage = [&](int buf, int st) {
#pragma unroll
    for (int sub = 0; sub < 2; ++sub) {
      const int tile = (st << 1) + sub;
#pragma unroll
      for (int it = 0; it < 2; ++it) {
        int seg = (w << 1) + it;
        int row = (seg << 3) + srow;
        gload16(&Kb[(size_t)(rb + (tile << 6) + row) * 1024 + cb + scol],
                (char*)Ks[buf][sub] + seg * 1024);
        gload16(&VbT[(size_t)((bh << 6) + row) * 2048 + (tile << 6) + scol],
                (char*)Vs[buf][sub] + seg * 1024);
      }
    }
  };

  // Q direct to registers: qf[g][kk] = Q[qt*128 + w*32 + g*16 + lr][cb + kk*32 + lg*8 ..)
  bf16x8 qf[2][2];
#pragma unroll
  for (int g = 0; g < 2; ++g)
#pragma unroll
    for (int kk = 0; kk < 2; ++kk)
      qf[g][kk] = *(const bf16x8*)&Qb[(size_t)(rb + (qt << 7) + (w << 5) + (g << 4) + lr) * 1024
                                      + cb + (kk << 5) + (lg << 3)];

  kv_stage(0, 0);
  asm volatile("s_waitcnt vmcnt(0)" ::: "memory");
  __builtin_amdgcn_s_barrier();
  __builtin_amdgcn_sched_barrier(0);

  const f32x4 z4 = {0.f, 0.f, 0.f, 0.f};
  float lsum[2] = {0.f, 0.f};
  f32x4 Oacc[2][4] = {};   // [g][df]

  for (int st = 0; st < 16; ++st) {
    const int buf = st & 1;
    if (st < 15) kv_stage(buf ^ 1, st + 1);   // issued first: whole phase to land

#pragma unroll
    for (int sub = 0; sub < 2; ++sub) {
      const u16* Kc = Ks[buf][sub];
      const u16* Vc = Vs[buf][sub];

      // QK^T + exp2 + pack, per 16-key chunk c
      unsigned U[2][4][2];   // [g][c][half]
#pragma unroll
      for (int c = 0; c < 4; ++c) {
        bf16x8 kf0 = lds8(Kc, (c << 4) + lr, (lg << 4));
        bf16x8 kf1 = lds8(Kc, (c << 4) + lr, 64 + (lg << 4));
        f32x4 S[2];
        __builtin_amdgcn_s_setprio(1);
#pragma unroll
        for (int g = 0; g < 2; ++g) {
          S[g] = __builtin_amdgcn_mfma_f32_16x16x32_bf16(kf0, qf[g][0], z4, 0, 0, 0);
          S[g] = __builtin_amdgcn_mfma_f32_16x16x32_bf16(kf1, qf[g][1], S[g], 0, 0, 0);
        }
        __builtin_amdgcn_s_setprio(0);
#pragma unroll
        for (int g = 0; g < 2; ++g) {
          float q0 = exp2v(S[g][0]), q1 = exp2v(S[g][1]);
          float q2 = exp2v(S[g][2]), q3 = exp2v(S[g][3]);
          lsum[g] += (q0 + q1) + (q2 + q3);
          U[g][c][0] = pk2bf(q0, q1);
          U[g][c][1] = pk2bf(q2, q3);
        }
      }

      // O += P * V; V-frag is a single swizzled b128 (sigma-global layout)
#pragma unroll
      for (int kk2 = 0; kk2 < 2; ++kk2) {
        bf16x8 vf[4];
#pragma unroll
        for (int df = 0; df < 4; ++df)
          vf[df] = lds8(Vc, (df << 4) + lr, (kk2 << 6) + (lg << 4));
        __builtin_amdgcn_s_setprio(1);
#pragma unroll
        for (int g = 0; g < 2; ++g) {
          u32x4 pt;
          pt[0] = U[g][2 * kk2][0];     pt[1] = U[g][2 * kk2][1];
          pt[2] = U[g][2 * kk2 + 1][0]; pt[3] = U[g][2 * kk2 + 1][1];
          bf16x8 pa = *(const bf16x8*)&pt;
#pragma unroll
          for (int df = 0; df < 4; ++df)
            Oacc[g][df] = __builtin_amdgcn_mfma_f32_16x16x32_bf16(pa, vf[df], Oacc[g][df], 0, 0, 0);
        }
        __builtin_amdgcn_s_setprio(0);
      }
    }

    asm volatile("s_waitcnt vmcnt(0)" ::: "memory");
    __builtin_amdgcn_s_barrier();
    __builtin_amdgcn_sched_barrier(0);
  }

  // epilogue per group: reduce lsum across lg-halves, normalize, store
#pragma unroll
  for (int g = 0; g < 2; ++g) {
    float ls = lsum[g];
    ls += __shfl_xor(ls, 16);
    ls += __shfl_xor(ls, 32);
    float lq[4];
#pragma unroll
    for (int r = 0; r < 4; ++r) lq[r] = 1.f / __shfl(ls, (lg << 2) + r);
#pragma unroll
    for (int df = 0; df < 4; ++df)
#pragma unroll
      for (int r = 0; r < 4; ++r) {
        int row = (qt << 7) + (w << 5) + (g << 4) + (lg << 2) + r;
        int col = (df << 4) + lr;
        Ob[(size_t)(rb + row) * 1024 + cb + col] = f2bf(Oacc[g][df][r] * lq[r]);
      }
  }
}

// ---------------- launcher ----------------

extern "C" void kernel_launch(void* const* d_in, const int* in_sizes, int n_in,
                              void* d_out, int out_size, void* d_ws, size_t ws_size,
                              hipStream_t stream) {
  const float* x  = (const float*)d_in[0];
  const float* Wq = (const float*)d_in[1];
  const float* Wk = (const float*)d_in[2];
  const float* Wv = (const float*)d_in[3];
  const float* Wo = (const float*)d_in[4];
  float* out = (float*)d_out;

  char* ws = (char*)d_ws;
  u16* xb     = (u16*)(ws);                 // 8 MB (reused as Ob)
  u16* WqkvT  = (u16*)(ws + 8388608);       // 6 MB  [3072][1024]
  u16* WoT    = (u16*)(ws + 14680064);      // 2 MB
  u16* Qb     = (u16*)(ws + 16777216);      // 8 MB
  u16* Kb     = (u16*)(ws + 25165824);      // 8 MB
  u16* VbT    = (u16*)(ws + 33554432);      // 8 MB  [bh*64+dim][2048 pos, sigma-permuted]
  f32x2* ctab = (f32x2*)(ws + 41943040);    // 512 KB
  u16* Ob = xb;

  cast_x_k<<<2048, 256, 0, stream>>>(x, xb);
  dim3 gt(16, 16, 4);
  transpose_cast_k<<<gt, 256, 0, stream>>>(Wq, Wk, Wv, Wo, WqkvT, WoT);
  rope_table_k<<<256, 256, 0, stream>>>(ctab);

  dim3 gq(24, 32);
  gemm_qkv_k<<<gq, 256, 0, stream>>>(xb, WqkvT, Qb, Kb, VbT, ctab);

  attn_k<<<512, 256, 0, stream>>>(Qb, Kb, VbT, Ob);

  dim3 go(8, 64);
  gemm_out_k<<<go, 256, 0, stream>>>(Ob, WoT, out);
}